// Round 11
// baseline (713.137 us; speedup 1.0000x reference)
//
#include <hip/hip_runtime.h>
#include <hip/hip_cooperative_groups.h>

namespace cgx = cooperative_groups;

static constexpr int NN  = 6144;
static constexpr int NE  = 98304;
static constexpr int NF  = 128;
static constexpr int NT  = 16;
static constexpr int MN  = 10;
static constexpr int NCG = 5;
static constexpr int NSK = 50;
static constexpr int WPR = NN / 32;
static constexpr int TPB = 768;
static constexpr int NBLK = 256;
static constexpr int RPT = NN / TPB;   // 8 rows/thread
static constexpr int NW  = TPB / 64;   // 12 waves

static_assert(TPB * RPT == NN, "row mapping");

// workspace layout (float elements). T/C/D stored split: uint4 plane (cols 0-7)
// + u32 plane (cols 8-9), both 16B/4B aligned. BM (setup-only) aliases T4..D4.
static constexpr size_t OFF_M   = 0;                               // fp32 [NT][NN][10]
static constexpr size_t OFF_T4  = OFF_M  + (size_t)NT * NN * MN;   // uint4 [NT][NN]
static constexpr size_t OFF_T1  = OFF_T4 + (size_t)NT * NN * 4;    // u32   [NT][NN]
static constexpr size_t OFF_C4  = OFF_T1 + (size_t)NT * NN;
static constexpr size_t OFF_C1  = OFF_C4 + (size_t)NT * NN * 4;
static constexpr size_t OFF_D4  = OFF_C1 + (size_t)NT * NN;
static constexpr size_t OFF_D1  = OFF_D4 + (size_t)NT * NN * 4;
static constexpr size_t OFF_RS  = OFF_D1 + (size_t)NT * NN;
static constexpr size_t OFF_DEG = OFF_RS + NN;
static constexpr size_t OFF_CI  = OFF_DEG + NN;                    // ushort[2*NE]
static constexpr size_t OFF_NNZ = OFF_CI + NE;

// LDS: rows as uint4 (cols 0-7) + u32 (cols 8-9); packed reduction buffer
static constexpr int LDS_PL  = NN * 20;          // 122880 B
static constexpr int LDS_SP  = TPB * 7 * 4;      // 21504 B (stride 7: conflict-free)
static constexpr int LDS_DYN = LDS_PL + LDS_SP;  // 144384 B

__device__ __forceinline__ unsigned f2bf(float f) {            // fp32 -> bf16 (rne)
    unsigned u = __float_as_uint(f);
    return (u + 0x7fffu + ((u >> 16) & 1u)) >> 16;
}
__device__ __forceinline__ unsigned packbf(float a, float b) { return f2bf(a) | (f2bf(b) << 16); }
__device__ __forceinline__ float bflo(unsigned w) { return __uint_as_float(w << 16); }
__device__ __forceinline__ float bfhi(unsigned w) { return __uint_as_float(w & 0xffff0000u); }

extern __shared__ char sMem[];

__global__ __launch_bounds__(TPB) void tfgw_kernel(
    const float* __restrict__ x, const void* __restrict__ eiv,
    const float* __restrict__ tpl, const float* __restrict__ tf,
    const float* __restrict__ q0, const float* __restrict__ a0,
    float* __restrict__ out, float* __restrict__ W)
{
    __shared__ float sC2[MN * MN];
    __shared__ float sq[MN], scq[MN], sqC2[MN], sNSQ[MN];
    __shared__ unsigned svp[5];        // v packed bf16-pairs (the v rows actually use)
    __shared__ unsigned svP2[5];       // v two iterations ago (2-cycle guard)
    __shared__ float sCv[5];
    __shared__ float sRed[3 * NW];
    __shared__ float sBC[2];
    __shared__ float sDots[4];

    const int tid = threadIdx.x;
    const int bid = blockIdx.x;

    unsigned* BM    = (unsigned*)(W + OFF_T4);  // aliased; dead after setup
    int* rowst      = (int*)(W + OFF_RS);
    int* degi       = (int*)(W + OFF_DEG);
    unsigned short* colix = (unsigned short*)(W + OFF_CI);
    int* nnzc       = (int*)(W + OFF_NNZ);
    float* Mw  = W + OFF_M;

    uint4*    PL4x = (uint4*)sMem;                        // [NN]: cols 0-7
    unsigned* PL1x = (unsigned*)(sMem + NN * 16);         // [NN]: cols 8-9
    unsigned* sPp  = (unsigned*)(sMem + LDS_PL);          // [TPB*7] packed partials

    const float alpha  = 1.f / (1.f + __expf(-a0[0]));
    const float invn   = 1.f / (float)NN;
    const float alpha2 = 2.f * alpha;
    const float oma    = 1.f - alpha;

    cgx::grid_group grid = cgx::this_grid();

    // ---- P0: zero bitmap + nnz ----
    for (int idx = bid * TPB + tid; idx < NN * WPR; idx += NBLK * TPB) BM[idx] = 0u;
    if (bid == 0 && tid == 0) *nnzc = 0;
    grid.sync();

    // ---- P1: adjacency bits + feature cost M (sTF overlays sMem) ----
    {
        const unsigned* uw = (const unsigned*)eiv;
        const bool is64 = (uw[1] == 0u && uw[3] == 0u && uw[5] == 0u);
        for (int e = bid * TPB + tid; e < NE; e += NBLK * TPB) {
            int s, d;
            if (is64) {
                s = (int)((const long long*)eiv)[e];
                d = (int)((const long long*)eiv)[NE + e];
            } else {
                s = ((const int*)eiv)[e];
                d = ((const int*)eiv)[NE + e];
            }
            atomicOr(&BM[(size_t)s * WPR + (d >> 5)], 1u << (d & 31));
            atomicOr(&BM[(size_t)d * WPR + (s >> 5)], 1u << (s & 31));
        }
        float* sTF = (float*)sMem;
        const int t = bid >> 4, rb = bid & 15;
        for (int k = tid; k < MN * NF; k += TPB) sTF[k] = tf[t * MN * NF + k];
        __syncthreads();
        if (tid < MN) {
            float s = 0.f;
            for (int k = 0; k < NF; ++k) { float v = sTF[tid * NF + k]; s += v * v; }
            sNSQ[tid] = s;
        }
        __syncthreads();
        if (tid < 384) {
            const int i = rb * 384 + tid;
            const float4* x4 = (const float4*)(x + (size_t)i * NF);
            const float4* t4 = (const float4*)sTF;
            float acc[MN]; float xn = 0.f;
            #pragma unroll
            for (int j = 0; j < MN; ++j) acc[j] = 0.f;
            for (int k4 = 0; k4 < NF / 4; ++k4) {
                float4 xv = x4[k4];
                xn += xv.x * xv.x + xv.y * xv.y + xv.z * xv.z + xv.w * xv.w;
                #pragma unroll
                for (int j = 0; j < MN; ++j) {
                    float4 tv = t4[j * (NF / 4) + k4];
                    acc[j] += xv.x * tv.x + xv.y * tv.y + xv.z * tv.z + xv.w * tv.w;
                }
            }
            float* Mrow = Mw + (size_t)t * NN * MN + (size_t)i * MN;
            #pragma unroll
            for (int j = 0; j < MN; ++j) Mrow[j] = xn + sNSQ[j] - 2.f * acc[j];
        }
    }
    grid.sync();

    // ---- P2: degrees + CSR (ushort cols) ----
    {
        const int i = bid * TPB + tid;
        if (i < NN) {
            int cnt = 0;
            for (int w = 0; w < WPR; ++w) cnt += __popc(BM[(size_t)i * WPR + w]);
            int st = atomicAdd(nnzc, cnt);
            rowst[i] = st; degi[i] = cnt;
            int p = st;
            for (int w = 0; w < WPR; ++w) {
                unsigned m = BM[(size_t)i * WPR + w];
                while (m) { int b = __ffs(m) - 1; m &= m - 1; colix[p++] = (unsigned short)((w << 5) + b); }
            }
        }
    }
    grid.sync();     // last grid sync

    if (bid >= NT) return;

    // ================= block t owns template t =================
    const int t = bid;
    float* Mb = Mw + (size_t)t * NN * MN;
    uint4*    Tb4 = (uint4*)(W + OFF_T4) + (size_t)t * NN;
    unsigned* Tb1 = (unsigned*)(W + OFF_T1) + (size_t)t * NN;
    uint4*    Cb4 = (uint4*)(W + OFF_C4) + (size_t)t * NN;
    unsigned* Cb1 = (unsigned*)(W + OFF_C1) + (size_t)t * NN;
    uint4*    Db4 = (uint4*)(W + OFF_D4) + (size_t)t * NN;
    unsigned* Db1 = (unsigned*)(W + OFF_D1) + (size_t)t * NN;

    if (tid == 0) {
        float qv[MN]; float qm = -1e30f;
        for (int j = 0; j < MN; ++j) { qv[j] = q0[t * MN + j]; qm = fmaxf(qm, qv[j]); }
        float qs = 0.f;
        for (int j = 0; j < MN; ++j) { qv[j] = __expf(qv[j] - qm); qs += qv[j]; }
        for (int j = 0; j < MN; ++j) { qv[j] /= qs; sq[j] = qv[j]; }
        for (int j = 0; j < MN; ++j) {
            float s2 = 0.f, s1 = 0.f;
            for (int k = 0; k < MN; ++k) {
                float cjk = tpl[t * MN * MN + j * MN + k];
                s2 += cjk * cjk * qv[k];
                s1 += tpl[t * MN * MN + k * MN + j] * qv[k];
            }
            scq[j] = s2; sqC2[j] = s1;
        }
    }
    for (int k = tid; k < MN * MN; k += TPB) sC2[k] = tpl[t * MN * MN + k];
    __syncthreads();

    for (int cgi = 0; cgi < NCG; ++cgi) {
        // ---- tau from previous dots; tau==0 (cgi>0) => fixed point ----
        if (tid == 0) {
            float tau = 0.f;
            if (cgi > 0) {
                float a = -2.f * alpha * sDots[3];
                float b = oma * sDots[0] + alpha * (sDots[1] - 4.f * sDots[2]);
                if (a > 0.f) tau = fminf(fmaxf(-b / (2.f * a + 1e-16f), 0.f), 1.f);
                else         tau = (a + b < 0.f) ? 1.f : 0.f;
            }
            sBC[0] = tau;
        }
        if (tid < 5) svP2[tid] = 0xFFFFFFFFu;   // invalidate 2-cycle history per CG step
        __syncthreads();
        const float tau = sBC[0];
        if (cgi > 0 && tau == 0.f) break;

        // ---- Phase A: update T,C (bf16 globals; dd from planes); g -> planes ----
        float gmax = 0.f;
        #pragma unroll
        for (int k = 0; k < RPT; ++k) {
            const int r = tid + k * TPB;
            const float cp = (float)degi[r] * invn;
            float C[MN];
            if (cgi == 0) {
                uint4 tw4; unsigned tw1;
                uint4 cw4; unsigned cw1;
                tw4.x = packbf(sq[0]*invn, sq[1]*invn); tw4.y = packbf(sq[2]*invn, sq[3]*invn);
                tw4.z = packbf(sq[4]*invn, sq[5]*invn); tw4.w = packbf(sq[6]*invn, sq[7]*invn);
                tw1   = packbf(sq[8]*invn, sq[9]*invn);
                cw4.x = packbf(cp*sqC2[0], cp*sqC2[1]); cw4.y = packbf(cp*sqC2[2], cp*sqC2[3]);
                cw4.z = packbf(cp*sqC2[4], cp*sqC2[5]); cw4.w = packbf(cp*sqC2[6], cp*sqC2[7]);
                cw1   = packbf(cp*sqC2[8], cp*sqC2[9]);
                Tb4[r] = tw4; Tb1[r] = tw1; Cb4[r] = cw4; Cb1[r] = cw1;
                C[0]=bflo(cw4.x); C[1]=bfhi(cw4.x); C[2]=bflo(cw4.y); C[3]=bfhi(cw4.y);
                C[4]=bflo(cw4.z); C[5]=bfhi(cw4.z); C[6]=bflo(cw4.w); C[7]=bfhi(cw4.w);
                C[8]=bflo(cw1);   C[9]=bfhi(cw1);
            } else {
                float dd[MN];
                uint4 a = PL4x[r]; unsigned b4 = PL1x[r];
                dd[0]=bflo(a.x); dd[1]=bfhi(a.x); dd[2]=bflo(a.y); dd[3]=bfhi(a.y);
                dd[4]=bflo(a.z); dd[5]=bfhi(a.z); dd[6]=bflo(a.w); dd[7]=bfhi(a.w);
                dd[8]=bflo(b4);  dd[9]=bfhi(b4);
                uint4 tw4 = Tb4[r]; unsigned tw1 = Tb1[r];
                uint4 cw4 = Cb4[r]; unsigned cw1 = Cb1[r];
                uint4 Dw4 = Db4[r]; unsigned Dw1 = Db1[r];
                float T[MN], Dd[MN];
                T[0]=bflo(tw4.x); T[1]=bfhi(tw4.x); T[2]=bflo(tw4.y); T[3]=bfhi(tw4.y);
                T[4]=bflo(tw4.z); T[5]=bfhi(tw4.z); T[6]=bflo(tw4.w); T[7]=bfhi(tw4.w);
                T[8]=bflo(tw1);   T[9]=bfhi(tw1);
                C[0]=bflo(cw4.x); C[1]=bfhi(cw4.x); C[2]=bflo(cw4.y); C[3]=bfhi(cw4.y);
                C[4]=bflo(cw4.z); C[5]=bfhi(cw4.z); C[6]=bflo(cw4.w); C[7]=bfhi(cw4.w);
                C[8]=bflo(cw1);   C[9]=bfhi(cw1);
                Dd[0]=bflo(Dw4.x); Dd[1]=bfhi(Dw4.x); Dd[2]=bflo(Dw4.y); Dd[3]=bfhi(Dw4.y);
                Dd[4]=bflo(Dw4.z); Dd[5]=bfhi(Dw4.z); Dd[6]=bflo(Dw4.w); Dd[7]=bfhi(Dw4.w);
                Dd[8]=bflo(Dw1);   Dd[9]=bfhi(Dw1);
                #pragma unroll
                for (int j = 0; j < MN; ++j) { T[j] += tau * dd[j]; C[j] += tau * Dd[j]; }
                uint4 ntw4; unsigned ntw1; uint4 ncw4; unsigned ncw1;
                ntw4.x = packbf(T[0],T[1]); ntw4.y = packbf(T[2],T[3]);
                ntw4.z = packbf(T[4],T[5]); ntw4.w = packbf(T[6],T[7]);
                ntw1   = packbf(T[8],T[9]);
                ncw4.x = packbf(C[0],C[1]); ncw4.y = packbf(C[2],C[3]);
                ncw4.z = packbf(C[4],C[5]); ncw4.w = packbf(C[6],C[7]);
                ncw1   = packbf(C[8],C[9]);
                Tb4[r] = ntw4; Tb1[r] = ntw1; Cb4[r] = ncw4; Cb1[r] = ncw1;
                C[0]=bflo(ncw4.x); C[1]=bfhi(ncw4.x); C[2]=bflo(ncw4.y); C[3]=bfhi(ncw4.y);
                C[4]=bflo(ncw4.z); C[5]=bfhi(ncw4.z); C[6]=bflo(ncw4.w); C[7]=bfhi(ncw4.w);
                C[8]=bflo(ncw1);   C[9]=bfhi(ncw1);
            }
            float g[MN];
            #pragma unroll
            for (int h = 0; h < 5; ++h) {
                float2 mv = *(const float2*)(Mb + (size_t)r * MN + 2*h);
                g[2*h]   = oma * mv.x + alpha2 * (cp + scq[2*h]   - 2.f * C[2*h]);
                g[2*h+1] = oma * mv.y + alpha2 * (cp + scq[2*h+1] - 2.f * C[2*h+1]);
                gmax = fmaxf(gmax, fmaxf(__builtin_fabsf(g[2*h]), __builtin_fabsf(g[2*h+1])));
            }
            PL4x[r] = make_uint4(packbf(g[0],g[1]), packbf(g[2],g[3]),
                                 packbf(g[4],g[5]), packbf(g[6],g[7]));
            PL1x[r] = packbf(g[8], g[9]);
        }
        #pragma unroll
        for (int d = 32; d; d >>= 1) gmax = fmaxf(gmax, __shfl_xor(gmax, d));
        if ((tid & 63) == 0) sRed[tid >> 6] = gmax;
        __syncthreads();
        if (tid == 0) {
            float m = sRed[0];
            for (int w = 1; w < NW; ++w) m = fmaxf(m, sRed[w]);
            sBC[1] = 1.f / (0.05f * m + 1e-8f);
        }
        __syncthreads();
        const float invreg = sBC[1];

        // ---- Phase B: E = exp(-g*invreg), in place (own rows only; no barrier) ----
        #pragma unroll
        for (int k = 0; k < RPT; ++k) {
            const int r = tid + k * TPB;
            uint4 a = PL4x[r]; unsigned b4 = PL1x[r];
            float g[MN];
            g[0]=bflo(a.x); g[1]=bfhi(a.x); g[2]=bflo(a.y); g[3]=bfhi(a.y);
            g[4]=bflo(a.z); g[5]=bfhi(a.z); g[6]=bflo(a.w); g[7]=bfhi(a.w);
            g[8]=bflo(b4);  g[9]=bfhi(b4);
            float e[MN];
            #pragma unroll
            for (int j = 0; j < MN; ++j) e[j] = __expf(-g[j] * invreg);
            PL4x[r] = make_uint4(packbf(e[0],e[1]), packbf(e[2],e[3]),
                                 packbf(e[4],e[5]), packbf(e[6],e[7]));
            PL1x[r] = packbf(e[8], e[9]);
        }

        // ---- Sinkhorn iter 0 (u = 1) — only for cgi==0; else warm-start ----
        if (cgi == 0) {
            float a[MN];
            #pragma unroll
            for (int j = 0; j < MN; ++j) a[j] = 0.f;
            #pragma unroll
            for (int k = 0; k < RPT; ++k) {
                const int r = tid + k * TPB;
                uint4 q = PL4x[r]; unsigned b4 = PL1x[r];
                a[0]+=bflo(q.x); a[1]+=bfhi(q.x); a[2]+=bflo(q.y); a[3]+=bfhi(q.y);
                a[4]+=bflo(q.z); a[5]+=bfhi(q.z); a[6]+=bflo(q.w); a[7]+=bfhi(q.w);
                a[8]+=bflo(b4);  a[9]+=bfhi(b4);
            }
            #pragma unroll
            for (int p = 0; p < 5; ++p) sPp[tid * 7 + p] = packbf(a[2*p], a[2*p+1]);
            __syncthreads();
            if (tid < 320) {
                const int p = tid >> 6, c = tid & 63;
                float s0 = 0.f, s1 = 0.f;
                #pragma unroll
                for (int kk = 0; kk < NW; ++kk) {
                    unsigned w = sPp[(c + (kk << 6)) * 7 + p];
                    s0 += bflo(w); s1 += bfhi(w);
                }
                #pragma unroll
                for (int d = 32; d; d >>= 1) { s0 += __shfl_xor(s0, d); s1 += __shfl_xor(s1, d); }
                if (c == 0) svp[p] = packbf(sq[2*p] / s0, sq[2*p+1] / s1);
            }
            __syncthreads();
        }

        // ---- Sinkhorn fused (u,v): exit when quantized v is stationary or 2-cycles ----
        for (int it = 1; it <= NSK; ++it) {
            float vv[MN];
            #pragma unroll
            for (int p = 0; p < 5; ++p) {
                unsigned w = svp[p];
                vv[2*p] = bflo(w); vv[2*p+1] = bfhi(w);
            }
            float a[MN];
            #pragma unroll
            for (int j = 0; j < MN; ++j) a[j] = 0.f;
            #pragma unroll
            for (int k = 0; k < RPT; ++k) {
                const int r = tid + k * TPB;
                uint4 q = PL4x[r]; unsigned b4 = PL1x[r];
                float e[MN];
                e[0]=bflo(q.x); e[1]=bfhi(q.x); e[2]=bflo(q.y); e[3]=bfhi(q.y);
                e[4]=bflo(q.z); e[5]=bfhi(q.z); e[6]=bflo(q.w); e[7]=bfhi(q.w);
                e[8]=bflo(b4);  e[9]=bfhi(b4);
                float R = 0.f;
                #pragma unroll
                for (int j = 0; j < MN; ++j) R += e[j] * vv[j];
                const float u = invn * __builtin_amdgcn_rcpf(R);
                #pragma unroll
                for (int j = 0; j < MN; ++j) a[j] += e[j] * u;
            }
            #pragma unroll
            for (int p = 0; p < 5; ++p) sPp[tid * 7 + p] = packbf(a[2*p], a[2*p+1]);
            __syncthreads();
            if (tid < 320) {
                const int p = tid >> 6, c = tid & 63;
                float s0 = 0.f, s1 = 0.f;
                #pragma unroll
                for (int kk = 0; kk < NW; ++kk) {
                    unsigned w = sPp[(c + (kk << 6)) * 7 + p];
                    s0 += bflo(w); s1 += bfhi(w);
                }
                #pragma unroll
                for (int d = 32; d; d >>= 1) { s0 += __shfl_xor(s0, d); s1 += __shfl_xor(s1, d); }
                if (c == 0) {
                    unsigned pw = packbf(sq[2*p] / s0, sq[2*p+1] / s1);
                    unsigned old = svp[p], old2 = svP2[p];
                    sCv[p] = (pw == old || pw == old2) ? 1.f : 0.f;
                    svP2[p] = old;
                    svp[p] = pw;
                }
            }
            __syncthreads();
            if (sCv[0] + sCv[1] + sCv[2] + sCv[3] + sCv[4] == 5.f) break;
        }

        // ---- dT phase: u recomputed from final v (always consistent); dots; planes <- dd ----
        {
            float vv[MN];
            #pragma unroll
            for (int p = 0; p < 5; ++p) {
                unsigned w = svp[p];
                vv[2*p] = bflo(w); vv[2*p+1] = bfhi(w);
            }
            float sMdT = 0.f, sCdT = 0.f, sCTdT = 0.f;
            #pragma unroll
            for (int k = 0; k < RPT; ++k) {
                const int r = tid + k * TPB;
                const float cp = (float)degi[r] * invn;
                uint4 q = PL4x[r]; unsigned b4 = PL1x[r];
                float e[MN], dd[MN];
                e[0]=bflo(q.x); e[1]=bfhi(q.x); e[2]=bflo(q.y); e[3]=bfhi(q.y);
                e[4]=bflo(q.z); e[5]=bfhi(q.z); e[6]=bflo(q.w); e[7]=bfhi(q.w);
                e[8]=bflo(b4);  e[9]=bfhi(b4);
                float R = 0.f;
                #pragma unroll
                for (int j = 0; j < MN; ++j) R += e[j] * vv[j];
                const float u = invn * __builtin_amdgcn_rcpf(R);
                uint4 tw4 = Tb4[r]; unsigned tw1 = Tb1[r];
                uint4 cw4 = Cb4[r]; unsigned cw1 = Cb1[r];
                float T[MN], C[MN];
                T[0]=bflo(tw4.x); T[1]=bfhi(tw4.x); T[2]=bflo(tw4.y); T[3]=bfhi(tw4.y);
                T[4]=bflo(tw4.z); T[5]=bfhi(tw4.z); T[6]=bflo(tw4.w); T[7]=bfhi(tw4.w);
                T[8]=bflo(tw1);   T[9]=bfhi(tw1);
                C[0]=bflo(cw4.x); C[1]=bfhi(cw4.x); C[2]=bflo(cw4.y); C[3]=bfhi(cw4.y);
                C[4]=bflo(cw4.z); C[5]=bfhi(cw4.z); C[6]=bflo(cw4.w); C[7]=bfhi(cw4.w);
                C[8]=bflo(cw1);   C[9]=bfhi(cw1);
                #pragma unroll
                for (int h = 0; h < 5; ++h) {
                    float2 mv = *(const float2*)(Mb + (size_t)r * MN + 2*h);
                    float d0 = u * e[2*h]   * vv[2*h]   - T[2*h];
                    float d1 = u * e[2*h+1] * vv[2*h+1] - T[2*h+1];
                    dd[2*h] = d0; dd[2*h+1] = d1;
                    sMdT  += mv.x * d0 + mv.y * d1;
                    sCdT  += (cp + scq[2*h]) * d0 + (cp + scq[2*h+1]) * d1;
                    sCTdT += C[2*h] * d0 + C[2*h+1] * d1;
                }
                PL4x[r] = make_uint4(packbf(dd[0],dd[1]), packbf(dd[2],dd[3]),
                                     packbf(dd[4],dd[5]), packbf(dd[6],dd[7]));
                PL1x[r] = packbf(dd[8], dd[9]);
            }
            #pragma unroll
            for (int d = 32; d; d >>= 1) {
                sMdT  += __shfl_xor(sMdT, d);
                sCdT  += __shfl_xor(sCdT, d);
                sCTdT += __shfl_xor(sCTdT, d);
            }
            if ((tid & 63) == 0) {
                const int w = tid >> 6;
                sRed[w] = sMdT; sRed[NW + w] = sCdT; sRed[2*NW + w] = sCTdT;
            }
            __syncthreads();   // dots staged AND dd planes visible block-wide
            if (tid == 0) {
                float r0 = 0.f, r1 = 0.f, r2 = 0.f;
                for (int w = 0; w < NW; ++w) { r0 += sRed[w]; r1 += sRed[NW+w]; r2 += sRed[2*NW+w]; }
                sDots[0] = r0; sDots[1] = r1; sDots[2] = r2;
            }
        }

        // ---- SpMM: D = C1 dT C2 (gather dd planes), sA = <D,dd>; D -> globals ----
        {
            float dot = 0.f;
            #pragma unroll
            for (int k = 0; k < RPT; ++k) {
                const int r = tid + k * TPB;
                float y[MN];
                #pragma unroll
                for (int j = 0; j < MN; ++j) y[j] = 0.f;
                const int st = rowst[r], dg = degi[r];
                const unsigned short* cl = colix + st;
                for (int e = 0; e < dg; ++e) {
                    const int j = cl[e];
                    uint4 q = PL4x[j]; unsigned b4 = PL1x[j];
                    y[0] += bflo(q.x); y[1] += bfhi(q.x);
                    y[2] += bflo(q.y); y[3] += bfhi(q.y);
                    y[4] += bflo(q.z); y[5] += bfhi(q.z);
                    y[6] += bflo(q.w); y[7] += bfhi(q.w);
                    y[8] += bflo(b4);  y[9] += bfhi(b4);
                }
                uint4 q = PL4x[r]; unsigned b4 = PL1x[r];
                float dd[MN];
                dd[0]=bflo(q.x); dd[1]=bfhi(q.x); dd[2]=bflo(q.y); dd[3]=bfhi(q.y);
                dd[4]=bflo(q.z); dd[5]=bfhi(q.z); dd[6]=bflo(q.w); dd[7]=bfhi(q.w);
                dd[8]=bflo(b4);  dd[9]=bfhi(b4);
                float o[MN];
                #pragma unroll
                for (int h = 0; h < 5; ++h) {
                    float o0 = 0.f, o1 = 0.f;
                    #pragma unroll
                    for (int j = 0; j < MN; ++j) {
                        o0 += y[j] * sC2[j * MN + 2*h];
                        o1 += y[j] * sC2[j * MN + 2*h + 1];
                    }
                    o[2*h] = o0; o[2*h+1] = o1;
                    dot += o0 * dd[2*h] + o1 * dd[2*h+1];
                }
                Db4[r] = make_uint4(packbf(o[0],o[1]), packbf(o[2],o[3]),
                                    packbf(o[4],o[5]), packbf(o[6],o[7]));
                Db1[r] = packbf(o[8], o[9]);
            }
            #pragma unroll
            for (int d = 32; d; d >>= 1) dot += __shfl_xor(dot, d);
            if ((tid & 63) == 0) sRed[tid >> 6] = dot;
            __syncthreads();
            if (tid == 0) {
                float s = 0.f;
                for (int w = 0; w < NW; ++w) s += sRed[w];
                sDots[3] = s;
            }
            __syncthreads();
        }
    }

    // ---- F: final tau + objective (T,C,D from bf16 globals; dd from planes) ----
    if (tid == 0) {
        float a = -2.f * alpha * sDots[3];
        float b = oma * sDots[0] + alpha * (sDots[1] - 4.f * sDots[2]);
        float tau;
        if (a > 0.f) tau = fminf(fmaxf(-b / (2.f * a + 1e-16f), 0.f), 1.f);
        else         tau = (a + b < 0.f) ? 1.f : 0.f;
        sBC[0] = tau;
    }
    __syncthreads();
    {
        const float tau = sBC[0];
        float gw = 0.f, wass = 0.f;
        #pragma unroll
        for (int k = 0; k < RPT; ++k) {
            const int r = tid + k * TPB;
            const float cp = (float)degi[r] * invn;
            uint4 q = PL4x[r]; unsigned b4 = PL1x[r];
            float dd[MN];
            dd[0]=bflo(q.x); dd[1]=bfhi(q.x); dd[2]=bflo(q.y); dd[3]=bfhi(q.y);
            dd[4]=bflo(q.z); dd[5]=bfhi(q.z); dd[6]=bflo(q.w); dd[7]=bfhi(q.w);
            dd[8]=bflo(b4);  dd[9]=bfhi(b4);
            uint4 tw4 = Tb4[r]; unsigned tw1 = Tb1[r];
            uint4 cw4 = Cb4[r]; unsigned cw1 = Cb1[r];
            uint4 Dw4 = Db4[r]; unsigned Dw1 = Db1[r];
            float T[MN], C[MN], Dd[MN];
            T[0]=bflo(tw4.x); T[1]=bfhi(tw4.x); T[2]=bflo(tw4.y); T[3]=bfhi(tw4.y);
            T[4]=bflo(tw4.z); T[5]=bfhi(tw4.z); T[6]=bflo(tw4.w); T[7]=bfhi(tw4.w);
            T[8]=bflo(tw1);   T[9]=bfhi(tw1);
            C[0]=bflo(cw4.x); C[1]=bfhi(cw4.x); C[2]=bflo(cw4.y); C[3]=bfhi(cw4.y);
            C[4]=bflo(cw4.z); C[5]=bfhi(cw4.z); C[6]=bflo(cw4.w); C[7]=bfhi(cw4.w);
            C[8]=bflo(cw1);   C[9]=bfhi(cw1);
            Dd[0]=bflo(Dw4.x); Dd[1]=bfhi(Dw4.x); Dd[2]=bflo(Dw4.y); Dd[3]=bfhi(Dw4.y);
            Dd[4]=bflo(Dw4.z); Dd[5]=bfhi(Dw4.z); Dd[6]=bflo(Dw4.w); Dd[7]=bfhi(Dw4.w);
            Dd[8]=bflo(Dw1);   Dd[9]=bfhi(Dw1);
            #pragma unroll
            for (int h = 0; h < 5; ++h) {
                float2 mv = *(const float2*)(Mb + (size_t)r * MN + 2*h);
                float Tf0 = T[2*h]   + tau * dd[2*h];
                float Tf1 = T[2*h+1] + tau * dd[2*h+1];
                float Cf0 = C[2*h]   + tau * Dd[2*h];
                float Cf1 = C[2*h+1] + tau * Dd[2*h+1];
                gw   += (cp + scq[2*h]   - 2.f * Cf0) * Tf0
                      + (cp + scq[2*h+1] - 2.f * Cf1) * Tf1;
                wass += mv.x * Tf0 + mv.y * Tf1;
            }
        }
        #pragma unroll
        for (int d = 32; d; d >>= 1) {
            gw   += __shfl_xor(gw, d);
            wass += __shfl_xor(wass, d);
        }
        if ((tid & 63) == 0) { sRed[tid >> 6] = gw; sRed[NW + (tid >> 6)] = wass; }
        __syncthreads();
        if (tid == 0) {
            float g = 0.f, ws = 0.f;
            for (int w = 0; w < NW; ++w) { g += sRed[w]; ws += sRed[NW + w]; }
            out[t] = oma * ws + alpha * g;
        }
    }
}

extern "C" void kernel_launch(void* const* d_in, const int* in_sizes, int n_in,
                              void* d_out, int out_size, void* d_ws, size_t ws_size,
                              hipStream_t stream) {
    const float* x   = (const float*)d_in[0];
    const void*  ei  = d_in[1];
    const float* tpl = (const float*)d_in[2];
    const float* tfp = (const float*)d_in[3];
    const float* q0  = (const float*)d_in[4];
    const float* a0  = (const float*)d_in[5];
    float* outp = (float*)d_out;
    float* Wp   = (float*)d_ws;
    (void)hipFuncSetAttribute(reinterpret_cast<const void*>(&tfgw_kernel),
                              hipFuncAttributeMaxDynamicSharedMemorySize, LDS_DYN);
    void* args[] = { &x, &ei, &tpl, &tfp, &q0, &a0, &outp, &Wp };
    hipLaunchCooperativeKernel(reinterpret_cast<const void*>(&tfgw_kernel),
                               dim3(NBLK), dim3(TPB), args, LDS_DYN, stream);
}